// Round 5
// baseline (187.451 us; speedup 1.0000x reference)
//
#include <hip/hip_runtime.h>
#include <hip/hip_bf16.h>

// B=512, A=4, D=6, N=1365, E=128. Level starts {0,1,5,21,85,341}.
// One block per batch tree, 512 thr (8 waves). All 4 level-1 subtrees merged:
// 24 phases (16 leaf M=64, 4 L4 M=64 dual, L3 M=64 dual, L2 M=16, L1 M=4,
// root M=1), ONE barrier per phase. Pipeline: [issue n+1 | compute n |
// store n+1 | sync] so gather latency hides behind MFMA. W fragments in VGPRs
// (256-VGPR budget, no spill). Pure function of d_in.
#define NTOK 1365
#define ED   128
#define STR  136   // bf16 LDS row stride: 272 B, 16B-aligned, <=2-way bank alias

typedef __attribute__((ext_vector_type(8))) short short8;
typedef __attribute__((ext_vector_type(4))) float f32x4;

#define MFMA(a,b,c) __builtin_amdgcn_mfma_f32_16x16x32_bf16((a),(b),(c),0,0,0)

__device__ __forceinline__ ushort f2bf(float f) {  // round-to-nearest-even
  union { float f; unsigned u; } v; v.f = f;
  unsigned r = v.u + 0x7fffu + ((v.u >> 16) & 1u);
  return (ushort)(r >> 16);
}
__device__ __forceinline__ ushort4 cvt4(float4 f) {
  ushort4 u; u.x = f2bf(f.x); u.y = f2bf(f.y); u.z = f2bf(f.z); u.w = f2bf(f.w);
  return u;
}
__device__ __forceinline__ short8 pack8(float4 a, float4 b) {
  union { ushort us[8]; short8 s8; } t;
  t.us[0]=f2bf(a.x); t.us[1]=f2bf(a.y); t.us[2]=f2bf(a.z); t.us[3]=f2bf(a.w);
  t.us[4]=f2bf(b.x); t.us[5]=f2bf(b.y); t.us[6]=f2bf(b.z); t.us[7]=f2bf(b.w);
  return t.s8;
}

// LDS: floats PM[8*132]+bC[128]+bS4[128] = 5248 B; bf16 rows:
// Xe0 64 + Xe1 64 + CS4 256 + CS3 64 + CS2 16 + CS1 4 = 468 rows * 272 B
#define SM_BYTES (5248 + 468 * STR * 2)   // 132544 B < 160 KiB

__global__ __launch_bounds__(512) void tree_kernel(
    const int* __restrict__ tokens, const float* __restrict__ emb,
    const float* __restrict__ WcW,  const float* __restrict__ Wcb,
    const float* __restrict__ WsW,  const float* __restrict__ Wsb,
    float* __restrict__ out) {
  extern __shared__ char smem[];
  float*  PM  = (float*)smem;          // [8][132] per-wave col maxima
  float*  bC  = PM + 8*132;
  float*  bS4 = bC + 128;              // 4*Ws_b
  ushort* Xe0 = (ushort*)(bS4 + 128);  // staging buf 0 (64 rows)
  ushort* Xe1 = Xe0 + 64*STR;          // staging buf 1
  ushort* CS4 = Xe1 + 64*STR;          // leaf child-sums, 256 rows (= L4 node idx)
  ushort* CS3 = CS4 + 256*STR;         // 64 rows (= L3 node idx)
  ushort* CS2 = CS3 + 64*STR;          // 16 rows (= L2 node idx); row 0 reused for H1
  ushort* CS1 = CS2 + 16*STR;          // 4 rows  (= L1 node idx)

  const int  tid = threadIdx.x;
  const int  b   = blockIdx.x;
  const long tokbase = (long)b * NTOK;
  const int  w    = tid >> 6;          // wave 0..7
  const int  lane = tid & 63;
  const int  n16  = lane & 15;
  const int  quad = lane >> 4;
  const int  mtg  = w >> 2, ntg = w & 3;   // 2x4 wave grid for M=64 phases
  const int  kof  = quad * 8;
  const int  csm  = w*16 + n16;            // small-phase column

  // ---- resident B fragments (global -> VGPR, once per block) ----
  short8 Bc64[2][4], Bs64[2][4], BcS[4], BsS[4];
  #pragma unroll
  for (int jt = 0; jt < 2; jt++)
    #pragma unroll
    for (int kb = 0; kb < 4; kb++) {
      const float* pc = WcW + (ntg*32 + jt*16 + n16)*ED + kb*32 + kof;
      Bc64[jt][kb] = pack8(((const float4*)pc)[0], ((const float4*)pc)[1]);
      const float* ps = WsW + (ntg*32 + jt*16 + n16)*ED + kb*32 + kof;
      Bs64[jt][kb] = pack8(((const float4*)ps)[0], ((const float4*)ps)[1]);
    }
  #pragma unroll
  for (int kb = 0; kb < 4; kb++) {
    const float* pc = WcW + csm*ED + kb*32 + kof;
    BcS[kb] = pack8(((const float4*)pc)[0], ((const float4*)pc)[1]);
    const float* ps = WsW + csm*ED + kb*32 + kof;
    BsS[kb] = pack8(((const float4*)ps)[0], ((const float4*)ps)[1]);
  }

  if (tid < 128) { bC[tid] = Wcb[tid]; bS4[tid] = 4.f*Wsb[tid]; }
  for (int i = tid; i < 8*132; i += 512) PM[i] = 0.f;

  float pm[2] = {0.f, 0.f};            // M=64-phase cols ntg*32+j*16+n16 (relu floor)
  float pms   = 0.f;                   // small-phase col csm

  // ---- pipelined gather: issue into regs now, cvt+store to LDS after compute ----
  float4 R0, R1, R2, R3;
  auto issue64 = [&](int nodeofs) {          // 64 rows, 8 thr/row, 64B/thread
    const int r = tid >> 3, p = tid & 7;
    const float4* src = (const float4*)(emb + (long)tokens[tokbase + nodeofs + r] * ED) + (p << 2);
    R0 = src[0]; R1 = src[1]; R2 = src[2]; R3 = src[3];
  };
  auto store64 = [&](ushort* Xe) {
    const int r = tid >> 3, p = tid & 7;
    short8* d = (short8*)(Xe + r*STR + (p << 4));
    d[0] = pack8(R0, R1); d[1] = pack8(R2, R3);
  };
  auto issueN = [&](int nodeofs, int nrows) { // nrows in {16,4,1}, 32 thr/row
    const int r = tid >> 5, p = tid & 31;
    if (r < nrows) R0 = ((const float4*)(emb + (long)tokens[tokbase + nodeofs + r] * ED))[p];
  };
  auto storeN = [&](ushort* Xe, int nrows) {
    const int r = tid >> 5, p = tid & 31;
    if (r < nrows) *(ushort4*)(Xe + r*STR + (p << 2)) = cvt4(R0);
  };

  // ---- M=64 phase: acc = Xe@Wc^T (+ csrc@Ws^T); epilogue: relu-max + child-sums ----
  auto phase64 = [&](const ushort* Xe, const ushort* csrc, ushort* csdst, int csrow0) {
    f32x4 acc[2][2];
    #pragma unroll
    for (int i = 0; i < 2; i++)
      #pragma unroll
      for (int j = 0; j < 2; j++) acc[i][j] = (f32x4){0.f,0.f,0.f,0.f};
    #pragma unroll
    for (int kb = 0; kb < 4; kb++) {
      const int ko = kb*32 + kof;
      short8 a0 = *(const short8*)(Xe + (mtg*32      + n16)*STR + ko);
      short8 a1 = *(const short8*)(Xe + (mtg*32 + 16 + n16)*STR + ko);
      acc[0][0]=MFMA(a0,Bc64[0][kb],acc[0][0]); acc[0][1]=MFMA(a0,Bc64[1][kb],acc[0][1]);
      acc[1][0]=MFMA(a1,Bc64[0][kb],acc[1][0]); acc[1][1]=MFMA(a1,Bc64[1][kb],acc[1][1]);
      if (csrc) {
        short8 c0 = *(const short8*)(csrc + (mtg*32      + n16)*STR + ko);
        short8 c1 = *(const short8*)(csrc + (mtg*32 + 16 + n16)*STR + ko);
        acc[0][0]=MFMA(c0,Bs64[0][kb],acc[0][0]); acc[0][1]=MFMA(c0,Bs64[1][kb],acc[0][1]);
        acc[1][0]=MFMA(c1,Bs64[0][kb],acc[1][0]); acc[1][1]=MFMA(c1,Bs64[1][kb],acc[1][1]);
      }
    }
    #pragma unroll
    for (int i = 0; i < 2; i++) {
      const int p = mtg*8 + i*4 + quad;        // parent row within this 64-chunk
      #pragma unroll
      for (int j = 0; j < 2; j++) {
        const int   c  = ntg*32 + j*16 + n16;
        const float bb = csrc ? (bC[c] + bS4[c]) : bC[c];
        f32x4 A = acc[i][j];
        float h0=A[0]+bb, h1=A[1]+bb, h2=A[2]+bb, h3=A[3]+bb;
        pm[j] = fmaxf(pm[j], fmaxf(fmaxf(h0,h1), fmaxf(h2,h3)));
        csdst[(csrow0 + p)*STR + c] = f2bf(A[0]+A[1]+A[2]+A[3] + 4.f*bb);
      }
    }
  };

  // ---- small phase (M<=16), always dual-chain; one 16x16 tile per wave ----
  // mode 16: M=16, write 4 child-sum rows; mode 4: M=4, write row 0 (= H1);
  // mode 0: M=1, relu-max only.
  auto smallphase = [&](const ushort* Xe, const ushort* csrc, int mode, ushort* csdst) {
    f32x4 acc = (f32x4){0.f,0.f,0.f,0.f};
    #pragma unroll
    for (int kb = 0; kb < 4; kb++) {
      const int ko = kb*32 + kof;
      short8 a  = *(const short8*)(Xe   + n16*STR + ko);
      acc = MFMA(a, BcS[kb], acc);
      short8 a2 = *(const short8*)(csrc + n16*STR + ko);
      acc = MFMA(a2, BsS[kb], acc);
    }
    const float bb = bC[csm] + bS4[csm];
    if (mode == 16) {
      float h0=acc[0]+bb, h1=acc[1]+bb, h2=acc[2]+bb, h3=acc[3]+bb;
      pms = fmaxf(pms, fmaxf(fmaxf(h0,h1), fmaxf(h2,h3)));
      csdst[quad*STR + csm] = f2bf(acc[0]+acc[1]+acc[2]+acc[3] + 4.f*bb);
    } else if (mode == 4) {
      if (quad == 0) {
        float h0=acc[0]+bb, h1=acc[1]+bb, h2=acc[2]+bb, h3=acc[3]+bb;
        pms = fmaxf(pms, fmaxf(fmaxf(h0,h1), fmaxf(h2,h3)));
        csdst[csm] = f2bf(acc[0]+acc[1]+acc[2]+acc[3] + 4.f*bb);  // = H1 (sum of h1)
      }
    } else {
      if (quad == 0) pms = fmaxf(pms, acc[0] + bb);               // root h0
    }
  };

  // ---- 24-phase driver, one barrier per phase ----
  ushort* XB[2] = {Xe0, Xe1};
  int cur = 0;
  issue64(341); store64(XB[0]);
  __syncthreads();

  for (int g = 0; g < 16; g++) {             // P0..P15: leaves (nodes 341+)
    if (g < 15) issue64(341 + (g+1)*64); else issue64(85);
    phase64(XB[cur], nullptr, CS4, g*16);    // CS4 row = leaf>>2 = L4 idx
    store64(XB[cur^1]);
    __syncthreads(); cur ^= 1;
  }
  for (int q = 0; q < 4; q++) {              // P16..P19: L4 (nodes 85+)
    if (q < 3) issue64(85 + (q+1)*64); else issue64(21);
    phase64(XB[cur], CS4 + q*64*STR, CS3, q*16);  // CS3 row = L3 idx
    store64(XB[cur^1]);
    __syncthreads(); cur ^= 1;
  }
  {                                          // P20: L3 (nodes 21..84, M=64)
    issueN(5, 16);
    phase64(XB[cur], CS3, CS2, 0);           // CS2 row = L2 idx
    storeN(XB[cur^1], 16);
    __syncthreads(); cur ^= 1;
  }
  {                                          // P21: L2 (nodes 5..20, M=16)
    issueN(1, 4);
    smallphase(XB[cur], CS2, 16, CS1);       // CS1 row = L1 idx
    storeN(XB[cur^1], 4);
    __syncthreads(); cur ^= 1;
  }
  {                                          // P22: L1 (nodes 1..4, M=4)
    issueN(0, 1);
    smallphase(XB[cur], CS1, 4, CS2);        // CS2 row 0 <- H1 = sum of 4 h1
    storeN(XB[cur^1], 1);
    __syncthreads(); cur ^= 1;
  }
  smallphase(XB[cur], CS2, 0, nullptr);      // P23: root (node 0)

  // ---- merge per-lane maxima -> PM -> out ----
  #pragma unroll
  for (int j = 0; j < 2; j++) {
    float v = pm[j];
    v = fmaxf(v, __shfl_xor(v, 16, 64));
    v = fmaxf(v, __shfl_xor(v, 32, 64));
    if (quad == 0) {
      float* s = PM + w*132 + ntg*32 + j*16 + n16;
      *s = fmaxf(*s, v);
    }
  }
  {
    float v = pms;
    v = fmaxf(v, __shfl_xor(v, 16, 64));
    v = fmaxf(v, __shfl_xor(v, 32, 64));
    if (quad == 0) {
      float* s = PM + w*132 + csm;
      *s = fmaxf(*s, v);
    }
  }
  __syncthreads();
  if (tid < 128) {
    float m = 0.f;
    #pragma unroll
    for (int r = 0; r < 8; r++) m = fmaxf(m, PM[r*132 + tid]);
    out[(long)b*ED + tid] = m;
  }
}

extern "C" void kernel_launch(void* const* d_in, const int* in_sizes, int n_in,
                              void* d_out, int out_size, void* d_ws, size_t ws_size,
                              hipStream_t stream) {
  const int*   tokens = (const int*)d_in[0];
  const float* emb    = (const float*)d_in[1];
  const float* WcW    = (const float*)d_in[2];
  const float* Wcb    = (const float*)d_in[3];
  const float* WsW    = (const float*)d_in[4];
  const float* Wsb    = (const float*)d_in[5];
  float* out = (float*)d_out;
  (void)d_ws; (void)ws_size;

  hipFuncSetAttribute(reinterpret_cast<const void*>(tree_kernel),
                      hipFuncAttributeMaxDynamicSharedMemorySize, SM_BYTES);
  tree_kernel<<<512, 512, SM_BYTES, stream>>>(tokens, emb, WcW, Wcb, WsW, Wsb, out);
}

// Round 6
// 170.407 us; speedup vs baseline: 1.1000x; 1.1000x over previous
//
#include <hip/hip_runtime.h>
#include <hip/hip_bf16.h>

// B=512, A=4, D=6, N=1365, E=128. Level starts {0,1,5,21,85,341}.
// One block per batch tree, 512 thr (8 waves). 24 phases, one barrier each:
// per quarter q: 4 leaf M=64 phases -> CS4[0..63], then L4 q (dual) -> CS3;
// then L3 (M=64 dual) -> CS2, L2 (M=16) -> CS1, L1 (M=4) -> H1, root (M=1).
// All phases share one column mapping (cols ntg*32+j*16+n16) so Wc/Ws
// fragments live once in VGPRs (no BcS/BsS, no spill at 256-VGPR budget).
// Gathers are depth-2 software-pipelined (Ra/Rb register sets, Xe dbuf).
// Pure function of d_in: no workspace, no atomics, no memset.
#define NTOK 1365
#define ED   128
#define STR  136   // bf16 LDS row stride: 272 B, 16B-aligned, balanced banks

typedef __attribute__((ext_vector_type(8))) short short8;
typedef __attribute__((ext_vector_type(4))) float f32x4;

#define MFMA(a,b,c) __builtin_amdgcn_mfma_f32_16x16x32_bf16((a),(b),(c),0,0,0)

__device__ __forceinline__ ushort f2bf(float f) {  // round-to-nearest-even
  union { float f; unsigned u; } v; v.f = f;
  unsigned r = v.u + 0x7fffu + ((v.u >> 16) & 1u);
  return (ushort)(r >> 16);
}
__device__ __forceinline__ ushort4 cvt4(float4 f) {
  ushort4 u; u.x = f2bf(f.x); u.y = f2bf(f.y); u.z = f2bf(f.z); u.w = f2bf(f.w);
  return u;
}
__device__ __forceinline__ short8 pack8(float4 a, float4 b) {
  union { ushort us[8]; short8 s8; } t;
  t.us[0]=f2bf(a.x); t.us[1]=f2bf(a.y); t.us[2]=f2bf(a.z); t.us[3]=f2bf(a.w);
  t.us[4]=f2bf(b.x); t.us[5]=f2bf(b.y); t.us[6]=f2bf(b.z); t.us[7]=f2bf(b.w);
  return t.s8;
}

// LDS: PM 8*128 floats (4096 B) + bf16 rows: Xe0 64, Xe1 64, CS4 64, CS3 64,
// CS2 16, CS1 4 = 276 rows * 272 B = 75072 B. Total 79168 B.
#define SM_BYTES (4096 + 276 * STR * 2)

__global__ __launch_bounds__(512, 2) void tree_kernel(
    const int* __restrict__ tokens, const float* __restrict__ emb,
    const float* __restrict__ WcW,  const float* __restrict__ Wcb,
    const float* __restrict__ WsW,  const float* __restrict__ Wsb,
    float* __restrict__ out) {
  extern __shared__ char smem[];
  float*  PM  = (float*)smem;            // [8][128] per-wave col maxima
  ushort* Xe0 = (ushort*)(PM + 1024);    // staging buf 0 (64 rows)
  ushort* Xe1 = Xe0 + 64*STR;            // staging buf 1
  ushort* CS4 = Xe1 + 64*STR;            // leaf child-sums, 64 rows (per quarter)
  ushort* CS3 = CS4 + 64*STR;            // 64 rows (= L3 node idx)
  ushort* CS2 = CS3 + 64*STR;            // 16 rows; row 0 reused as H1
  ushort* CS1 = CS2 + 16*STR;            // 4 rows

  const int  tid = threadIdx.x;
  const int  b   = blockIdx.x;
  const long tokbase = (long)b * NTOK;
  const int  w    = tid >> 6;            // wave 0..7
  const int  lane = tid & 63;
  const int  n16  = lane & 15;
  const int  quad = lane >> 4;
  const int  mtg  = w >> 2, ntg = w & 3; // 2x4 wave grid for M=64 phases
  const int  kof  = quad * 8;

  // ---- biases in registers (all phases share the column mapping) ----
  float bcv[2], bsv[2];
  #pragma unroll
  for (int j = 0; j < 2; j++) {
    const int c = ntg*32 + j*16 + n16;
    bcv[j] = Wcb[c]; bsv[j] = 4.f * Wsb[c];
  }

  // ---- resident B fragments: Wc and Ws, once per block ----
  short8 Bc[2][4], Bs[2][4];
  #pragma unroll
  for (int jt = 0; jt < 2; jt++)
    #pragma unroll
    for (int kb = 0; kb < 4; kb++) {
      const float* pc = WcW + (ntg*32 + jt*16 + n16)*ED + kb*32 + kof;
      Bc[jt][kb] = pack8(((const float4*)pc)[0], ((const float4*)pc)[1]);
      const float* ps = WsW + (ntg*32 + jt*16 + n16)*ED + kb*32 + kof;
      Bs[jt][kb] = pack8(((const float4*)ps)[0], ((const float4*)ps)[1]);
    }

  for (int i = tid; i < 1024; i += 512) PM[i] = 0.f;

  float pm[2] = {0.f, 0.f};              // relu floor, cols ntg*32+j*16+n16

  // ---- depth-2 pipelined gathers: two register sets, chosen by constants ----
  float4 Ra[4], Rb[4];
  auto issue64 = [&](float4 (&R)[4], int ofs) {   // 64 rows, 8 thr/row
    const int r = tid >> 3, p = tid & 7;
    const float4* src = (const float4*)(emb + (long)tokens[tokbase + ofs + r]*ED) + (p << 2);
    R[0] = src[0]; R[1] = src[1]; R[2] = src[2]; R[3] = src[3];
  };
  auto store64 = [&](const float4 (&R)[4], ushort* Xe) {
    const int r = tid >> 3, p = tid & 7;
    short8* d = (short8*)(Xe + r*STR + (p << 4));
    d[0] = pack8(R[0], R[1]); d[1] = pack8(R[2], R[3]);
  };
  auto issueN = [&](float4 (&R)[4], int ofs, int nrows) { // 32 thr/row
    const int r = tid >> 5, p = tid & 31;
    if (r < nrows) R[0] = ((const float4*)(emb + (long)tokens[tokbase + ofs + r]*ED))[p];
  };
  auto storeN = [&](const float4 (&R)[4], ushort* Xe, int nrows) {
    const int r = tid >> 5, p = tid & 31;
    if (r < nrows) *(ushort4*)(Xe + r*STR + (p << 2)) = cvt4(R[0]);
  };

  // ---- M=64 phase: acc = Xe@Wc^T (+ csrc@Ws^T); relu-max + child-quad-sums ----
  auto phase64 = [&](const ushort* Xe, const ushort* csrc, ushort* csdst, int csrow0) {
    f32x4 acc[2][2];
    #pragma unroll
    for (int i = 0; i < 2; i++)
      #pragma unroll
      for (int j = 0; j < 2; j++) acc[i][j] = (f32x4){0.f,0.f,0.f,0.f};
    #pragma unroll
    for (int kb = 0; kb < 4; kb++) {
      const int ko = kb*32 + kof;
      short8 a0 = *(const short8*)(Xe + (mtg*32      + n16)*STR + ko);
      short8 a1 = *(const short8*)(Xe + (mtg*32 + 16 + n16)*STR + ko);
      acc[0][0]=MFMA(a0,Bc[0][kb],acc[0][0]); acc[0][1]=MFMA(a0,Bc[1][kb],acc[0][1]);
      acc[1][0]=MFMA(a1,Bc[0][kb],acc[1][0]); acc[1][1]=MFMA(a1,Bc[1][kb],acc[1][1]);
      if (csrc) {
        short8 c0 = *(const short8*)(csrc + (mtg*32      + n16)*STR + ko);
        short8 c1 = *(const short8*)(csrc + (mtg*32 + 16 + n16)*STR + ko);
        acc[0][0]=MFMA(c0,Bs[0][kb],acc[0][0]); acc[0][1]=MFMA(c0,Bs[1][kb],acc[0][1]);
        acc[1][0]=MFMA(c1,Bs[0][kb],acc[1][0]); acc[1][1]=MFMA(c1,Bs[1][kb],acc[1][1]);
      }
    }
    #pragma unroll
    for (int i = 0; i < 2; i++) {
      const int p = mtg*8 + i*4 + quad;          // C row / 4 = parent idx
      #pragma unroll
      for (int j = 0; j < 2; j++) {
        const float bb = csrc ? (bcv[j] + bsv[j]) : bcv[j];
        f32x4 A = acc[i][j];
        float h0=A[0]+bb, h1=A[1]+bb, h2=A[2]+bb, h3=A[3]+bb;
        pm[j] = fmaxf(pm[j], fmaxf(fmaxf(h0,h1), fmaxf(h2,h3)));
        csdst[(csrow0 + p)*STR + ntg*32 + j*16 + n16] =
            f2bf(A[0]+A[1]+A[2]+A[3] + 4.f*bb);
      }
    }
  };

  // ---- small phases (mtg==0 waves only), reuse Bc/Bs/bcv/bsv/pm ----
  // M=16 (L2): write CS1[quad]; M=4 (L1): write csdst row 0 (=H1); M=1: root.
  auto smallphase = [&](const ushort* Xe, const ushort* csrc, int M, ushort* csdst) {
    if (mtg != 0) return;
    const int ar = (M == 16) ? n16 : ((M == 4) ? (n16 & 3) : 0);  // row clamp
    f32x4 acc[2];
    acc[0] = (f32x4){0.f,0.f,0.f,0.f}; acc[1] = (f32x4){0.f,0.f,0.f,0.f};
    #pragma unroll
    for (int kb = 0; kb < 4; kb++) {
      const int ko = kb*32 + kof;
      short8 a  = *(const short8*)(Xe   + ar*STR + ko);
      short8 c2 = *(const short8*)(csrc + ar*STR + ko);
      acc[0] = MFMA(a,  Bc[0][kb], acc[0]); acc[1] = MFMA(a,  Bc[1][kb], acc[1]);
      acc[0] = MFMA(c2, Bs[0][kb], acc[0]); acc[1] = MFMA(c2, Bs[1][kb], acc[1]);
    }
    #pragma unroll
    for (int j = 0; j < 2; j++) {
      const float bb = bcv[j] + bsv[j];
      f32x4 A = acc[j];
      const int c = ntg*32 + j*16 + n16;
      if (M == 16) {
        float h0=A[0]+bb, h1=A[1]+bb, h2=A[2]+bb, h3=A[3]+bb;
        pm[j] = fmaxf(pm[j], fmaxf(fmaxf(h0,h1), fmaxf(h2,h3)));
        csdst[quad*STR + c] = f2bf(A[0]+A[1]+A[2]+A[3] + 4.f*bb);
      } else if (M == 4) {
        if (quad == 0) {
          float h0=A[0]+bb, h1=A[1]+bb, h2=A[2]+bb, h3=A[3]+bb;
          pm[j] = fmaxf(pm[j], fmaxf(fmaxf(h0,h1), fmaxf(h2,h3)));
          csdst[c] = f2bf(A[0]+A[1]+A[2]+A[3] + 4.f*bb);   // H1 = sum of 4 h1
        }
      } else {
        if (quad == 0) pm[j] = fmaxf(pm[j], A[0] + bb);    // root h0
      }
    }
  };

  // ---- 24-phase driver; phase n computes XB[n&1]; issue n+2 into slot n&1;
  //      store n+1 from slot (n+1)&1. ----
  ushort* XB[2] = {Xe0, Xe1};
  issue64(Ra, 341);            // P0: leaf(0,0)
  issue64(Rb, 341 + 64);       // P1: leaf(0,1)
  store64(Ra, XB[0]);
  __syncthreads();

  #pragma unroll
  for (int q = 0; q < 4; q++) {
    #pragma unroll
    for (int g = 0; g < 4; g++) {                 // phases n = 5q+g: leaf(q,g)
      const int n = 5*q + g;
      float4 (&Ri)[4] = (n & 1) ? Rb : Ra;
      if (g < 2)       issue64(Ri, 341 + q*256 + (g+2)*64);
      else if (g == 2) issue64(Ri, 85 + q*64);            // L4 q gather
      else { if (q < 3) issue64(Ri, 341 + (q+1)*256);     // leaf(q+1,0)
             else       issue64(Ri, 21); }                // L3 gather
      phase64(XB[n & 1], nullptr, CS4, g*16);
      float4 (&Rs)[4] = ((n+1) & 1) ? Rb : Ra;
      store64(Rs, XB[(n+1) & 1]);
      __syncthreads();
    }
    {                                             // phase n = 5q+4: L4 q (dual)
      const int n = 5*q + 4;
      float4 (&Ri)[4] = (n & 1) ? Rb : Ra;
      if (q < 3) issue64(Ri, 341 + (q+1)*256 + 64);       // leaf(q+1,1)
      else       issueN(Ri, 5, 16);                       // L2 gather
      phase64(XB[n & 1], CS4, CS3, q*16);
      float4 (&Rs)[4] = ((n+1) & 1) ? Rb : Ra;
      store64(Rs, XB[(n+1) & 1]);
      __syncthreads();
    }
  }
  // P20 (slot 0): L3 dual, 64 rows -> CS2[0..15]
  issueN(Ra, 1, 4);                                       // L1 gather
  phase64(XB[0], CS3, CS2, 0);
  storeN(Rb, XB[1], 16);
  __syncthreads();
  // P21 (slot 1): L2, M=16 -> CS1[0..3]
  issueN(Rb, 0, 1);                                       // root gather
  smallphase(XB[1], CS2, 16, CS1);
  storeN(Ra, XB[0], 4);
  __syncthreads();
  // P22 (slot 0): L1, M=4 -> H1 (CS2 row 0)
  smallphase(XB[0], CS1, 4, CS2);
  storeN(Rb, XB[1], 1);
  __syncthreads();
  // P23 (slot 1): root, M=1
  smallphase(XB[1], CS2, 1, nullptr);

  // ---- merge per-lane maxima -> PM -> out ----
  #pragma unroll
  for (int j = 0; j < 2; j++) {
    float v = pm[j];
    v = fmaxf(v, __shfl_xor(v, 16, 64));
    v = fmaxf(v, __shfl_xor(v, 32, 64));
    if (quad == 0) PM[w*128 + ntg*32 + j*16 + n16] = v;
  }
  __syncthreads();
  if (tid < 128) {
    float m = 0.f;
    #pragma unroll
    for (int r = 0; r < 8; r++) m = fmaxf(m, PM[r*128 + tid]);
    out[(long)b*ED + tid] = m;
  }
}

extern "C" void kernel_launch(void* const* d_in, const int* in_sizes, int n_in,
                              void* d_out, int out_size, void* d_ws, size_t ws_size,
                              hipStream_t stream) {
  const int*   tokens = (const int*)d_in[0];
  const float* emb    = (const float*)d_in[1];
  const float* WcW    = (const float*)d_in[2];
  const float* Wcb    = (const float*)d_in[3];
  const float* WsW    = (const float*)d_in[4];
  const float* Wsb    = (const float*)d_in[5];
  float* out = (float*)d_out;
  (void)d_ws; (void)ws_size;

  hipFuncSetAttribute(reinterpret_cast<const void*>(tree_kernel),
                      hipFuncAttributeMaxDynamicSharedMemorySize, SM_BYTES);
  tree_kernel<<<512, 512, SM_BYTES, stream>>>(tokens, emb, WcW, Wcb, WsW, Wsb, out);
}

// Round 7
// 167.010 us; speedup vs baseline: 1.1224x; 1.0203x over previous
//
#include <hip/hip_runtime.h>
#include <hip/hip_bf16.h>

// B=512, A=4, D=6, N=1365, E=128. Level starts {0,1,5,21,85,341}.
// One block per batch tree, 512 thr (8 waves), 1 block/CU (LDS 79 KB).
// 24 phases, one barrier each; per quarter q: 4 leaf M=64 phases -> CS4,
// then L4 q (dual chain) -> CS3; then L3 (M=64 dual) -> CS2, L2 (M=16) ->
// CS1, L1 (M=4) -> H1, root (M=1). All phases share one column mapping so
// Wc/Ws fragments are VGPR-resident. __launch_bounds__(512,1): 1 block/CU
// declared -> 256-VGPR budget -> no scratch spill (R5/R6 failure mode).
// Driver is written as an explicit 24-phase sequence (no loops) so the
// depth-2 prefetch register sets RA/RB are never runtime-indexed.
// Pure function of d_in: no workspace, no atomics, no memset.
#define NTOK 1365
#define ED   128
#define STR  136   // bf16 LDS row stride: 272 B, 16B-aligned, balanced banks

typedef __attribute__((ext_vector_type(8))) short short8;
typedef __attribute__((ext_vector_type(4))) float f32x4;

#define MFMA(a,b,c) __builtin_amdgcn_mfma_f32_16x16x32_bf16((a),(b),(c),0,0,0)

__device__ __forceinline__ ushort f2bf(float f) {  // round-to-nearest-even
  union { float f; unsigned u; } v; v.f = f;
  unsigned r = v.u + 0x7fffu + ((v.u >> 16) & 1u);
  return (ushort)(r >> 16);
}
__device__ __forceinline__ ushort4 cvt4(float4 f) {
  ushort4 u; u.x = f2bf(f.x); u.y = f2bf(f.y); u.z = f2bf(f.z); u.w = f2bf(f.w);
  return u;
}
__device__ __forceinline__ short8 pack8(float4 a, float4 b) {
  union { ushort us[8]; short8 s8; } t;
  t.us[0]=f2bf(a.x); t.us[1]=f2bf(a.y); t.us[2]=f2bf(a.z); t.us[3]=f2bf(a.w);
  t.us[4]=f2bf(b.x); t.us[5]=f2bf(b.y); t.us[6]=f2bf(b.z); t.us[7]=f2bf(b.w);
  return t.s8;
}

// LDS: PM 8*128 floats (4096 B) + bf16 rows: Xe0 64, Xe1 64, CS4 64, CS3 64,
// CS2 16, CS1 4 = 276 rows * 272 B = 75072 B. Total 79168 B -> 1 block/CU.
#define SM_BYTES (4096 + 276 * STR * 2)

__global__ __launch_bounds__(512, 1) void tree_kernel(
    const int* __restrict__ tokens, const float* __restrict__ emb,
    const float* __restrict__ WcW,  const float* __restrict__ Wcb,
    const float* __restrict__ WsW,  const float* __restrict__ Wsb,
    float* __restrict__ out) {
  extern __shared__ char smem[];
  float*  PM  = (float*)smem;            // [8][128] per-wave col maxima
  ushort* Xe0 = (ushort*)(PM + 1024);    // staging buf 0 (64 rows)
  ushort* Xe1 = Xe0 + 64*STR;            // staging buf 1
  ushort* CS4 = Xe1 + 64*STR;            // leaf child-sums, 64 rows (per quarter)
  ushort* CS3 = CS4 + 64*STR;            // 64 rows (= L3 node idx)
  ushort* CS2 = CS3 + 64*STR;            // 16 rows; row 0 reused as H1
  ushort* CS1 = CS2 + 16*STR;            // 4 rows

  const int  tid = threadIdx.x;
  const int  b   = blockIdx.x;
  const long tokbase = (long)b * NTOK;
  const int  w    = tid >> 6;            // wave 0..7
  const int  lane = tid & 63;
  const int  n16  = lane & 15;
  const int  quad = lane >> 4;
  const int  mtg  = w >> 2, ntg = w & 3; // 2x4 wave grid for M=64 phases
  const int  kof  = quad * 8;

  // ---- biases in registers (all phases share the column mapping) ----
  float bcv[2], bsv[2];
  #pragma unroll
  for (int j = 0; j < 2; j++) {
    const int c = ntg*32 + j*16 + n16;
    bcv[j] = Wcb[c]; bsv[j] = 4.f * Wsb[c];
  }

  // ---- resident B fragments: Wc and Ws, once per block ----
  short8 Bc[2][4], Bs[2][4];
  #pragma unroll
  for (int jt = 0; jt < 2; jt++)
    #pragma unroll
    for (int kb = 0; kb < 4; kb++) {
      const float* pc = WcW + (ntg*32 + jt*16 + n16)*ED + kb*32 + kof;
      Bc[jt][kb] = pack8(((const float4*)pc)[0], ((const float4*)pc)[1]);
      const float* ps = WsW + (ntg*32 + jt*16 + n16)*ED + kb*32 + kof;
      Bs[jt][kb] = pack8(((const float4*)ps)[0], ((const float4*)ps)[1]);
    }

  for (int i = tid; i < 1024; i += 512) PM[i] = 0.f;

  float pm[2] = {0.f, 0.f};              // relu floor, cols ntg*32+j*16+n16

  // ---- depth-2 pipelined gathers: two named register sets ----
  float4 RA[4], RB[4];
  auto issue64 = [&](float4 (&R)[4], int ofs) {   // 64 rows, 8 thr/row
    const int r = tid >> 3, p = tid & 7;
    const float4* src = (const float4*)(emb + (long)tokens[tokbase + ofs + r]*ED) + (p << 2);
    R[0] = src[0]; R[1] = src[1]; R[2] = src[2]; R[3] = src[3];
  };
  auto store64 = [&](const float4 (&R)[4], ushort* Xe) {
    const int r = tid >> 3, p = tid & 7;
    short8* d = (short8*)(Xe + r*STR + (p << 4));
    d[0] = pack8(R[0], R[1]); d[1] = pack8(R[2], R[3]);
  };
  auto issueN = [&](float4 (&R)[4], int ofs, int nrows) { // 32 thr/row
    const int r = tid >> 5, p = tid & 31;
    if (r < nrows) R[0] = ((const float4*)(emb + (long)tokens[tokbase + ofs + r]*ED))[p];
  };
  auto storeN = [&](const float4 (&R)[4], ushort* Xe, int nrows) {
    const int r = tid >> 5, p = tid & 31;
    if (r < nrows) *(ushort4*)(Xe + r*STR + (p << 2)) = cvt4(R[0]);
  };

  // ---- M=64 phase: acc = Xe@Wc^T (+ csrc@Ws^T); relu-max + child-quad-sums ----
  auto phase64 = [&](const ushort* Xe, const ushort* csrc, ushort* csdst, int csrow0) {
    f32x4 acc[2][2];
    #pragma unroll
    for (int i = 0; i < 2; i++)
      #pragma unroll
      for (int j = 0; j < 2; j++) acc[i][j] = (f32x4){0.f,0.f,0.f,0.f};
    #pragma unroll
    for (int kb = 0; kb < 4; kb++) {
      const int ko = kb*32 + kof;
      short8 a0 = *(const short8*)(Xe + (mtg*32      + n16)*STR + ko);
      short8 a1 = *(const short8*)(Xe + (mtg*32 + 16 + n16)*STR + ko);
      acc[0][0]=MFMA(a0,Bc[0][kb],acc[0][0]); acc[0][1]=MFMA(a0,Bc[1][kb],acc[0][1]);
      acc[1][0]=MFMA(a1,Bc[0][kb],acc[1][0]); acc[1][1]=MFMA(a1,Bc[1][kb],acc[1][1]);
      if (csrc) {
        short8 c0 = *(const short8*)(csrc + (mtg*32      + n16)*STR + ko);
        short8 c1 = *(const short8*)(csrc + (mtg*32 + 16 + n16)*STR + ko);
        acc[0][0]=MFMA(c0,Bs[0][kb],acc[0][0]); acc[0][1]=MFMA(c0,Bs[1][kb],acc[0][1]);
        acc[1][0]=MFMA(c1,Bs[0][kb],acc[1][0]); acc[1][1]=MFMA(c1,Bs[1][kb],acc[1][1]);
      }
    }
    #pragma unroll
    for (int i = 0; i < 2; i++) {
      const int p = mtg*8 + i*4 + quad;          // C row / 4 = parent idx
      #pragma unroll
      for (int j = 0; j < 2; j++) {
        const float bb = csrc ? (bcv[j] + bsv[j]) : bcv[j];
        f32x4 A = acc[i][j];
        float h0=A[0]+bb, h1=A[1]+bb, h2=A[2]+bb, h3=A[3]+bb;
        pm[j] = fmaxf(pm[j], fmaxf(fmaxf(h0,h1), fmaxf(h2,h3)));
        csdst[(csrow0 + p)*STR + ntg*32 + j*16 + n16] =
            f2bf(A[0]+A[1]+A[2]+A[3] + 4.f*bb);
      }
    }
  };

  // ---- small phases (mtg==0 waves only), reuse Bc/Bs/bcv/bsv/pm ----
  auto smallphase = [&](const ushort* Xe, const ushort* csrc, int M, ushort* csdst) {
    if (mtg != 0) return;
    const int ar = (M == 16) ? n16 : ((M == 4) ? (n16 & 3) : 0);  // row clamp
    f32x4 acc[2];
    acc[0] = (f32x4){0.f,0.f,0.f,0.f}; acc[1] = (f32x4){0.f,0.f,0.f,0.f};
    #pragma unroll
    for (int kb = 0; kb < 4; kb++) {
      const int ko = kb*32 + kof;
      short8 a  = *(const short8*)(Xe   + ar*STR + ko);
      short8 c2 = *(const short8*)(csrc + ar*STR + ko);
      acc[0] = MFMA(a,  Bc[0][kb], acc[0]); acc[1] = MFMA(a,  Bc[1][kb], acc[1]);
      acc[0] = MFMA(c2, Bs[0][kb], acc[0]); acc[1] = MFMA(c2, Bs[1][kb], acc[1]);
    }
    #pragma unroll
    for (int j = 0; j < 2; j++) {
      const float bb = bcv[j] + bsv[j];
      f32x4 A = acc[j];
      const int c = ntg*32 + j*16 + n16;
      if (M == 16) {
        float h0=A[0]+bb, h1=A[1]+bb, h2=A[2]+bb, h3=A[3]+bb;
        pm[j] = fmaxf(pm[j], fmaxf(fmaxf(h0,h1), fmaxf(h2,h3)));
        csdst[quad*STR + c] = f2bf(A[0]+A[1]+A[2]+A[3] + 4.f*bb);
      } else if (M == 4) {
        if (quad == 0) {
          float h0=A[0]+bb, h1=A[1]+bb, h2=A[2]+bb, h3=A[3]+bb;
          pm[j] = fmaxf(pm[j], fmaxf(fmaxf(h0,h1), fmaxf(h2,h3)));
          csdst[c] = f2bf(A[0]+A[1]+A[2]+A[3] + 4.f*bb);   // H1 = sum of 4 h1
        }
      } else {
        if (quad == 0) pm[j] = fmaxf(pm[j], A[0] + bb);    // root h0
      }
    }
  };

  // ---- explicit 24-phase driver: phase n computes Xe(n&1); the gather for
  //      phase n+2 issues into RA/RB (parity n&1); phase n+1's registers
  //      (parity (n+1)&1) store into Xe((n+1)&1); then one barrier. ----
  issue64(RA, 341);                  // leaf(0,0)
  issue64(RB, 341 + 64);             // leaf(0,1)
  store64(RA, Xe0);
  __syncthreads();
  /*n=0 leaf(0,0)*/ issue64(RA, 341+128);     phase64(Xe0, nullptr, CS4,  0); store64(RB, Xe1); __syncthreads();
  /*n=1 leaf(0,1)*/ issue64(RB, 341+192);     phase64(Xe1, nullptr, CS4, 16); store64(RA, Xe0); __syncthreads();
  /*n=2 leaf(0,2)*/ issue64(RA, 85);          phase64(Xe0, nullptr, CS4, 32); store64(RB, Xe1); __syncthreads();
  /*n=3 leaf(0,3)*/ issue64(RB, 341+256);     phase64(Xe1, nullptr, CS4, 48); store64(RA, Xe0); __syncthreads();
  /*n=4 L4 q0   */ issue64(RA, 341+256+64);   phase64(Xe0, CS4,     CS3,  0); store64(RB, Xe1); __syncthreads();
  /*n=5 leaf(1,0)*/ issue64(RB, 341+256+128); phase64(Xe1, nullptr, CS4,  0); store64(RA, Xe0); __syncthreads();
  /*n=6 leaf(1,1)*/ issue64(RA, 341+256+192); phase64(Xe0, nullptr, CS4, 16); store64(RB, Xe1); __syncthreads();
  /*n=7 leaf(1,2)*/ issue64(RB, 85+64);       phase64(Xe1, nullptr, CS4, 32); store64(RA, Xe0); __syncthreads();
  /*n=8 leaf(1,3)*/ issue64(RA, 341+512);     phase64(Xe0, nullptr, CS4, 48); store64(RB, Xe1); __syncthreads();
  /*n=9 L4 q1   */ issue64(RB, 341+512+64);   phase64(Xe1, CS4,     CS3, 16); store64(RA, Xe0); __syncthreads();
  /*n=10 leaf(2,0)*/ issue64(RA, 341+512+128); phase64(Xe0, nullptr, CS4,  0); store64(RB, Xe1); __syncthreads();
  /*n=11 leaf(2,1)*/ issue64(RB, 341+512+192); phase64(Xe1, nullptr, CS4, 16); store64(RA, Xe0); __syncthreads();
  /*n=12 leaf(2,2)*/ issue64(RA, 85+128);      phase64(Xe0, nullptr, CS4, 32); store64(RB, Xe1); __syncthreads();
  /*n=13 leaf(2,3)*/ issue64(RB, 341+768);     phase64(Xe1, nullptr, CS4, 48); store64(RA, Xe0); __syncthreads();
  /*n=14 L4 q2   */ issue64(RA, 341+768+64);   phase64(Xe0, CS4,     CS3, 32); store64(RB, Xe1); __syncthreads();
  /*n=15 leaf(3,0)*/ issue64(RB, 341+768+128); phase64(Xe1, nullptr, CS4,  0); store64(RA, Xe0); __syncthreads();
  /*n=16 leaf(3,1)*/ issue64(RA, 341+768+192); phase64(Xe0, nullptr, CS4, 16); store64(RB, Xe1); __syncthreads();
  /*n=17 leaf(3,2)*/ issue64(RB, 85+192);      phase64(Xe1, nullptr, CS4, 32); store64(RA, Xe0); __syncthreads();
  /*n=18 leaf(3,3)*/ issue64(RA, 21);          phase64(Xe0, nullptr, CS4, 48); store64(RB, Xe1); __syncthreads();
  /*n=19 L4 q3   */ issueN(RB, 5, 16);         phase64(Xe1, CS4,     CS3, 48); store64(RA, Xe0); __syncthreads();
  /*n=20 L3 dual */ issueN(RA, 1, 4);          phase64(Xe0, CS3,     CS2,  0); storeN(RB, Xe1, 16); __syncthreads();
  /*n=21 L2 M=16 */ issueN(RB, 0, 1);          smallphase(Xe1, CS2, 16, CS1);  storeN(RA, Xe0, 4);  __syncthreads();
  /*n=22 L1 M=4  */                            smallphase(Xe0, CS1, 4,  CS2);  storeN(RB, Xe1, 1);  __syncthreads();
  /*n=23 root    */                            smallphase(Xe1, CS2, 1,  nullptr);

  // ---- merge per-lane maxima -> PM -> out ----
  #pragma unroll
  for (int j = 0; j < 2; j++) {
    float v = pm[j];
    v = fmaxf(v, __shfl_xor(v, 16, 64));
    v = fmaxf(v, __shfl_xor(v, 32, 64));
    if (quad == 0) PM[w*128 + ntg*32 + j*16 + n16] = v;
  }
  __syncthreads();
  if (tid < 128) {
    float m = 0.f;
    #pragma unroll
    for (int r = 0; r < 8; r++) m = fmaxf(m, PM[r*128 + tid]);
    out[(long)b*ED + tid] = m;
  }
}

extern "C" void kernel_launch(void* const* d_in, const int* in_sizes, int n_in,
                              void* d_out, int out_size, void* d_ws, size_t ws_size,
                              hipStream_t stream) {
  const int*   tokens = (const int*)d_in[0];
  const float* emb    = (const float*)d_in[1];
  const float* WcW    = (const float*)d_in[2];
  const float* Wcb    = (const float*)d_in[3];
  const float* WsW    = (const float*)d_in[4];
  const float* Wsb    = (const float*)d_in[5];
  float* out = (float*)d_out;
  (void)d_ws; (void)ws_size;

  hipFuncSetAttribute(reinterpret_cast<const void*>(tree_kernel),
                      hipFuncAttributeMaxDynamicSharedMemorySize, SM_BYTES);
  tree_kernel<<<512, 512, SM_BYTES, stream>>>(tokens, emb, WcW, Wcb, WsW, Wsb, out);
}

// Round 8
// 147.493 us; speedup vs baseline: 1.2709x; 1.1323x over previous
//
#include <hip/hip_runtime.h>
#include <hip/hip_bf16.h>

// B=512, A=4, D=6, N=1365, E=128. Level starts {0,1,5,21,85,341}.
// One block per batch tree, 512 thr (8 waves), 1 block/CU (LDS 111 KB).
// 24 phases, one barrier each; per quarter q: 4 leaf M=64 phases -> CS4,
// then L4 q (dual chain) -> CS3; then L3 (M=64 dual) -> CS2, L2 (M=16) ->
// CS1, L1 (M=4) -> H1, root (M=1). All phases share one column mapping.
// Register budget (R5-R7 lesson: allocator pins this kernel at 128 VGPRs and
// spills): Wc frags resident in VGPRs (used all 24 phases, 32 regs); Ws frags
// in LDS (used in ~6 dual phases, read per phase); depth-2 gather prefetch
// RA/RB (32 regs). Total demand ~105 < 128 -> no scratch spill.
// Pure function of d_in: no workspace, no atomics, no memset.
#define NTOK 1365
#define ED   128
#define STR  136   // bf16 LDS row stride: 272 B, 16B-aligned, balanced banks

typedef __attribute__((ext_vector_type(8))) short short8;
typedef __attribute__((ext_vector_type(4))) float f32x4;

#define MFMA(a,b,c) __builtin_amdgcn_mfma_f32_16x16x32_bf16((a),(b),(c),0,0,0)

__device__ __forceinline__ ushort f2bf(float f) {  // round-to-nearest-even
  union { float f; unsigned u; } v; v.f = f;
  unsigned r = v.u + 0x7fffu + ((v.u >> 16) & 1u);
  return (ushort)(r >> 16);
}
__device__ __forceinline__ ushort4 cvt4(float4 f) {
  ushort4 u; u.x = f2bf(f.x); u.y = f2bf(f.y); u.z = f2bf(f.z); u.w = f2bf(f.w);
  return u;
}
__device__ __forceinline__ short8 pack8(float4 a, float4 b) {
  union { ushort us[8]; short8 s8; } t;
  t.us[0]=f2bf(a.x); t.us[1]=f2bf(a.y); t.us[2]=f2bf(a.z); t.us[3]=f2bf(a.w);
  t.us[4]=f2bf(b.x); t.us[5]=f2bf(b.y); t.us[6]=f2bf(b.z); t.us[7]=f2bf(b.w);
  return t.s8;
}

// LDS: PM 8*128 floats (4096 B) + bf16 rows: WsL 128, Xe0 64, Xe1 64,
// CS4 64, CS3 64, CS2 16, CS1 4 = 404 rows * 272 B = 109888 B.
// Total 113984 B -> 1 block/CU.
#define SM_BYTES (4096 + 404 * STR * 2)

__global__ __attribute__((amdgpu_flat_work_group_size(512, 512),
                          amdgpu_waves_per_eu(2, 8)))
void tree_kernel(
    const int* __restrict__ tokens, const float* __restrict__ emb,
    const float* __restrict__ WcW,  const float* __restrict__ Wcb,
    const float* __restrict__ WsW,  const float* __restrict__ Wsb,
    float* __restrict__ out) {
  extern __shared__ char smem[];
  float*  PM  = (float*)smem;            // [8][128] per-wave col maxima
  ushort* WsL = (ushort*)(PM + 1024);    // Ws bf16, 128 rows
  ushort* Xe0 = WsL + 128*STR;           // staging buf 0 (64 rows)
  ushort* Xe1 = Xe0 + 64*STR;            // staging buf 1
  ushort* CS4 = Xe1 + 64*STR;            // leaf child-sums, 64 rows (per quarter)
  ushort* CS3 = CS4 + 64*STR;            // 64 rows (= L3 node idx)
  ushort* CS2 = CS3 + 64*STR;            // 16 rows; row 0 reused as H1
  ushort* CS1 = CS2 + 16*STR;            // 4 rows

  const int  tid = threadIdx.x;
  const int  b   = blockIdx.x;
  const long tokbase = (long)b * NTOK;
  const int  w    = tid >> 6;            // wave 0..7
  const int  lane = tid & 63;
  const int  n16  = lane & 15;
  const int  quad = lane >> 4;
  const int  mtg  = w >> 2, ntg = w & 3; // 2x4 wave grid for M=64 phases
  const int  kof  = quad * 8;

  // ---- biases in registers (all phases share the column mapping) ----
  float bcv[2], bsv[2];
  #pragma unroll
  for (int j = 0; j < 2; j++) {
    const int c = ntg*32 + j*16 + n16;
    bcv[j] = Wcb[c]; bsv[j] = 4.f * Wsb[c];
  }

  // ---- Wc fragments resident in VGPRs (hot: every phase) ----
  short8 Bc[2][4];
  #pragma unroll
  for (int jt = 0; jt < 2; jt++)
    #pragma unroll
    for (int kb = 0; kb < 4; kb++) {
      const float* pc = WcW + (ntg*32 + jt*16 + n16)*ED + kb*32 + kof;
      Bc[jt][kb] = pack8(((const float4*)pc)[0], ((const float4*)pc)[1]);
    }

  // ---- Ws staged to LDS as bf16 (warm: dual phases only) ----
  #pragma unroll
  for (int i = 0; i < 8; i++) {
    const int idx = tid + i*512;                 // float4 index over 128x128/4
    float4 f = ((const float4*)WsW)[idx];
    *(ushort4*)(WsL + (idx >> 5)*STR + ((idx & 31) << 2)) = cvt4(f);
  }

  for (int i = tid; i < 1024; i += 512) PM[i] = 0.f;

  float pm[2] = {0.f, 0.f};              // relu floor, cols ntg*32+j*16+n16

  // ---- depth-2 pipelined gathers: two named register sets ----
  float4 RA[4], RB[4];
  auto issue64 = [&](float4 (&R)[4], int ofs) {   // 64 rows, 8 thr/row
    const int r = tid >> 3, p = tid & 7;
    const float4* src = (const float4*)(emb + (long)tokens[tokbase + ofs + r]*ED) + (p << 2);
    R[0] = src[0]; R[1] = src[1]; R[2] = src[2]; R[3] = src[3];
  };
  auto store64 = [&](const float4 (&R)[4], ushort* Xe) {
    const int r = tid >> 3, p = tid & 7;
    short8* d = (short8*)(Xe + r*STR + (p << 4));
    d[0] = pack8(R[0], R[1]); d[1] = pack8(R[2], R[3]);
  };
  auto issueN = [&](float4 (&R)[4], int ofs, int nrows) { // 32 thr/row
    const int r = tid >> 5, p = tid & 31;
    if (r < nrows) R[0] = ((const float4*)(emb + (long)tokens[tokbase + ofs + r]*ED))[p];
  };
  auto storeN = [&](const float4 (&R)[4], ushort* Xe, int nrows) {
    const int r = tid >> 5, p = tid & 31;
    if (r < nrows) *(ushort4*)(Xe + r*STR + (p << 2)) = cvt4(R[0]);
  };

  // ---- M=64 phase: acc = Xe@Wc^T (+ csrc@Ws^T); relu-max + child-quad-sums ----
  auto phase64 = [&](const ushort* Xe, const ushort* csrc, ushort* csdst, int csrow0) {
    f32x4 acc[2][2];
    #pragma unroll
    for (int i = 0; i < 2; i++)
      #pragma unroll
      for (int j = 0; j < 2; j++) acc[i][j] = (f32x4){0.f,0.f,0.f,0.f};
    #pragma unroll
    for (int kb = 0; kb < 4; kb++) {
      const int ko = kb*32 + kof;
      short8 a0 = *(const short8*)(Xe + (mtg*32      + n16)*STR + ko);
      short8 a1 = *(const short8*)(Xe + (mtg*32 + 16 + n16)*STR + ko);
      acc[0][0]=MFMA(a0,Bc[0][kb],acc[0][0]); acc[0][1]=MFMA(a0,Bc[1][kb],acc[0][1]);
      acc[1][0]=MFMA(a1,Bc[0][kb],acc[1][0]); acc[1][1]=MFMA(a1,Bc[1][kb],acc[1][1]);
      if (csrc) {
        short8 c0 = *(const short8*)(csrc + (mtg*32      + n16)*STR + ko);
        short8 c1 = *(const short8*)(csrc + (mtg*32 + 16 + n16)*STR + ko);
        short8 s0 = *(const short8*)(WsL  + (ntg*32      + n16)*STR + ko);
        short8 s1 = *(const short8*)(WsL  + (ntg*32 + 16 + n16)*STR + ko);
        acc[0][0]=MFMA(c0,s0,acc[0][0]); acc[0][1]=MFMA(c0,s1,acc[0][1]);
        acc[1][0]=MFMA(c1,s0,acc[1][0]); acc[1][1]=MFMA(c1,s1,acc[1][1]);
      }
    }
    #pragma unroll
    for (int i = 0; i < 2; i++) {
      const int p = mtg*8 + i*4 + quad;          // C row / 4 = parent idx
      #pragma unroll
      for (int j = 0; j < 2; j++) {
        const float bb = csrc ? (bcv[j] + bsv[j]) : bcv[j];
        f32x4 A = acc[i][j];
        float h0=A[0]+bb, h1=A[1]+bb, h2=A[2]+bb, h3=A[3]+bb;
        pm[j] = fmaxf(pm[j], fmaxf(fmaxf(h0,h1), fmaxf(h2,h3)));
        csdst[(csrow0 + p)*STR + ntg*32 + j*16 + n16] =
            f2bf(A[0]+A[1]+A[2]+A[3] + 4.f*bb);
      }
    }
  };

  // ---- small phases (mtg==0 waves only), reuse Bc/WsL/bcv/bsv/pm ----
  auto smallphase = [&](const ushort* Xe, const ushort* csrc, int M, ushort* csdst) {
    if (mtg != 0) return;
    const int ar = (M == 16) ? n16 : ((M == 4) ? (n16 & 3) : 0);  // row clamp
    f32x4 acc[2];
    acc[0] = (f32x4){0.f,0.f,0.f,0.f}; acc[1] = (f32x4){0.f,0.f,0.f,0.f};
    #pragma unroll
    for (int kb = 0; kb < 4; kb++) {
      const int ko = kb*32 + kof;
      short8 a  = *(const short8*)(Xe   + ar*STR + ko);
      short8 c2 = *(const short8*)(csrc + ar*STR + ko);
      short8 s0 = *(const short8*)(WsL + (ntg*32      + n16)*STR + ko);
      short8 s1 = *(const short8*)(WsL + (ntg*32 + 16 + n16)*STR + ko);
      acc[0] = MFMA(a,  Bc[0][kb], acc[0]); acc[1] = MFMA(a,  Bc[1][kb], acc[1]);
      acc[0] = MFMA(c2, s0, acc[0]);        acc[1] = MFMA(c2, s1, acc[1]);
    }
    #pragma unroll
    for (int j = 0; j < 2; j++) {
      const float bb = bcv[j] + bsv[j];
      f32x4 A = acc[j];
      const int c = ntg*32 + j*16 + n16;
      if (M == 16) {
        float h0=A[0]+bb, h1=A[1]+bb, h2=A[2]+bb, h3=A[3]+bb;
        pm[j] = fmaxf(pm[j], fmaxf(fmaxf(h0,h1), fmaxf(h2,h3)));
        csdst[quad*STR + c] = f2bf(A[0]+A[1]+A[2]+A[3] + 4.f*bb);
      } else if (M == 4) {
        if (quad == 0) {
          float h0=A[0]+bb, h1=A[1]+bb, h2=A[2]+bb, h3=A[3]+bb;
          pm[j] = fmaxf(pm[j], fmaxf(fmaxf(h0,h1), fmaxf(h2,h3)));
          csdst[c] = f2bf(A[0]+A[1]+A[2]+A[3] + 4.f*bb);   // H1 = sum of 4 h1
        }
      } else {
        if (quad == 0) pm[j] = fmaxf(pm[j], A[0] + bb);    // root h0
      }
    }
  };

  // ---- explicit 24-phase driver: phase n computes Xe(n&1); the gather for
  //      phase n+2 issues into RA/RB (parity n&1); phase n+1's registers
  //      (parity (n+1)&1) store into Xe((n+1)&1); then one barrier. ----
  issue64(RA, 341);                  // leaf(0,0)
  issue64(RB, 341 + 64);             // leaf(0,1)
  store64(RA, Xe0);
  __syncthreads();
  /*n=0 leaf(0,0)*/ issue64(RA, 341+128);     phase64(Xe0, nullptr, CS4,  0); store64(RB, Xe1); __syncthreads();
  /*n=1 leaf(0,1)*/ issue64(RB, 341+192);     phase64(Xe1, nullptr, CS4, 16); store64(RA, Xe0); __syncthreads();
  /*n=2 leaf(0,2)*/ issue64(RA, 85);          phase64(Xe0, nullptr, CS4, 32); store64(RB, Xe1); __syncthreads();
  /*n=3 leaf(0,3)*/ issue64(RB, 341+256);     phase64(Xe1, nullptr, CS4, 48); store64(RA, Xe0); __syncthreads();
  /*n=4 L4 q0   */ issue64(RA, 341+256+64);   phase64(Xe0, CS4,     CS3,  0); store64(RB, Xe1); __syncthreads();
  /*n=5 leaf(1,0)*/ issue64(RB, 341+256+128); phase64(Xe1, nullptr, CS4,  0); store64(RA, Xe0); __syncthreads();
  /*n=6 leaf(1,1)*/ issue64(RA, 341+256+192); phase64(Xe0, nullptr, CS4, 16); store64(RB, Xe1); __syncthreads();
  /*n=7 leaf(1,2)*/ issue64(RB, 85+64);       phase64(Xe1, nullptr, CS4, 32); store64(RA, Xe0); __syncthreads();
  /*n=8 leaf(1,3)*/ issue64(RA, 341+512);     phase64(Xe0, nullptr, CS4, 48); store64(RB, Xe1); __syncthreads();
  /*n=9 L4 q1   */ issue64(RB, 341+512+64);   phase64(Xe1, CS4,     CS3, 16); store64(RA, Xe0); __syncthreads();
  /*n=10 leaf(2,0)*/ issue64(RA, 341+512+128); phase64(Xe0, nullptr, CS4,  0); store64(RB, Xe1); __syncthreads();
  /*n=11 leaf(2,1)*/ issue64(RB, 341+512+192); phase64(Xe1, nullptr, CS4, 16); store64(RA, Xe0); __syncthreads();
  /*n=12 leaf(2,2)*/ issue64(RA, 85+128);      phase64(Xe0, nullptr, CS4, 32); store64(RB, Xe1); __syncthreads();
  /*n=13 leaf(2,3)*/ issue64(RB, 341+768);     phase64(Xe1, nullptr, CS4, 48); store64(RA, Xe0); __syncthreads();
  /*n=14 L4 q2   */ issue64(RA, 341+768+64);   phase64(Xe0, CS4,     CS3, 32); store64(RB, Xe1); __syncthreads();
  /*n=15 leaf(3,0)*/ issue64(RB, 341+768+128); phase64(Xe1, nullptr, CS4,  0); store64(RA, Xe0); __syncthreads();
  /*n=16 leaf(3,1)*/ issue64(RA, 341+768+192); phase64(Xe0, nullptr, CS4, 16); store64(RB, Xe1); __syncthreads();
  /*n=17 leaf(3,2)*/ issue64(RB, 85+192);      phase64(Xe1, nullptr, CS4, 32); store64(RA, Xe0); __syncthreads();
  /*n=18 leaf(3,3)*/ issue64(RA, 21);          phase64(Xe0, nullptr, CS4, 48); store64(RB, Xe1); __syncthreads();
  /*n=19 L4 q3   */ issueN(RB, 5, 16);         phase64(Xe1, CS4,     CS3, 48); store64(RA, Xe0); __syncthreads();
  /*n=20 L3 dual */ issueN(RA, 1, 4);          phase64(Xe0, CS3,     CS2,  0); storeN(RB, Xe1, 16); __syncthreads();
  /*n=21 L2 M=16 */ issueN(RB, 0, 1);          smallphase(Xe1, CS2, 16, CS1);  storeN(RA, Xe0, 4);  __syncthreads();
  /*n=22 L1 M=4  */                            smallphase(Xe0, CS1, 4,  CS2);  storeN(RB, Xe1, 1);  __syncthreads();
  /*n=23 root    */                            smallphase(Xe1, CS2, 1,  nullptr);

  // ---- merge per-lane maxima -> PM -> out ----
  #pragma unroll
  for (int j = 0; j < 2; j++) {
    float v = pm[j];
    v = fmaxf(v, __shfl_xor(v, 16, 64));
    v = fmaxf(v, __shfl_xor(v, 32, 64));
    if (quad == 0) PM[w*128 + ntg*32 + j*16 + n16] = v;
  }
  __syncthreads();
  if (tid < 128) {
    float m = 0.f;
    #pragma unroll
    for (int r = 0; r < 8; r++) m = fmaxf(m, PM[r*128 + tid]);
    out[(long)b*ED + tid] = m;
  }
}

extern "C" void kernel_launch(void* const* d_in, const int* in_sizes, int n_in,
                              void* d_out, int out_size, void* d_ws, size_t ws_size,
                              hipStream_t stream) {
  const int*   tokens = (const int*)d_in[0];
  const float* emb    = (const float*)d_in[1];
  const float* WcW    = (const float*)d_in[2];
  const float* Wcb    = (const float*)d_in[3];
  const float* WsW    = (const float*)d_in[4];
  const float* Wsb    = (const float*)d_in[5];
  float* out = (float*)d_out;
  (void)d_ws; (void)ws_size;

  hipFuncSetAttribute(reinterpret_cast<const void*>(tree_kernel),
                      hipFuncAttributeMaxDynamicSharedMemorySize, SM_BYTES);
  tree_kernel<<<512, 512, SM_BYTES, stream>>>(tokens, emb, WcW, Wcb, WsW, Wsb, out);
}